// Round 7
// baseline (13.277 us; speedup 1.0000x reference)
//
#include <hip/hip_runtime.h>
#include <hip/hip_bf16.h>

// Constants from the reference
#define E_DIM 16
#define H_DIM 8
#define F_DIM 48
#define L_IN 384
#define L_OUT 384
#define SZ_B 4

#define NCHUNK 16           // l-chunks per bh
#define ROWS_PER_BLOCK 24
#define ROWS_PER_WAVE 6
#define TSTRIDE 20          // padded table row stride (floats): 80 B, 16B-aligned b128 rows

typedef float f32x4 __attribute__((ext_vector_type(4)));

// out[bh, l, m] = sum_d q[bh,l,d] * ( r_voice[l%8, m%8, d, h] + rt(l/8, m/8, d, h) )
//   rt(fp,fq,d,h) = fp>=fq ? e_past[fp-fq,d,h] : e_future[fq-fp,d,h]
// Block = (chunk, bh): 24 rows l = chunk*24 + lrow. Full tables staged once
// (fi-independent), 4 waves; wave w owns rows w*6..w*6+5.
// Phase A: all 6 dot-rows back-to-back (pipelined LDS reads, no fences).
// Single lgkmcnt(0) fence. Phase B: 12 coalesced float4 store instrs.
__global__ __launch_bounds__(256)
void bsa_fused_kernel(const float* __restrict__ q,
                      const float* __restrict__ r_voice,
                      const float* __restrict__ e_past,
                      const float* __restrict__ e_future,
                      float* __restrict__ out) {
    const int chunk = blockIdx.x;   // [0, 16)
    const int bh    = blockIdx.y;   // [0, 32)
    const int h     = bh & (H_DIM - 1);
    const int t     = threadIdx.x;  // [0, 256)
    const int w     = t >> 6;
    const int lane  = t & 63;

    // Table rows (stride 20): 0..47 past[diff], 48..95 future[diff], 96..159 voice
    __shared__ __attribute__((aligned(16))) float tabs[160 * TSTRIDE];           // 12.8 KB
    __shared__ __attribute__((aligned(16))) float qs[ROWS_PER_BLOCK * E_DIM];    // 1.5 KB
    __shared__ __attribute__((aligned(16))) float scratch[4][ROWS_PER_WAVE * 64];// 6 KB

    // Stage transposed tables (this block's h-plane). i = f*16+d; src = i*8+h.
    for (int i = t; i < F_DIM * E_DIM; i += 256) {
        const int f = i >> 4, d = i & 15;
        tabs[f * TSTRIDE + d]           = e_past [(size_t)i * H_DIM + h];
        tabs[(F_DIM + f) * TSTRIDE + d] = e_future[(size_t)i * H_DIM + h];
    }
    for (int i = t; i < 64 * E_DIM; i += 256) {
        const int r = i >> 4, d = i & 15;
        tabs[(96 + r) * TSTRIDE + d] = r_voice[(size_t)i * H_DIM + h];
    }
    // Stage this block's 24 q-rows (contiguous, coalesced)
    for (int i = t; i < ROWS_PER_BLOCK * E_DIM; i += 256)
        qs[i] = q[((size_t)bh * L_IN + chunk * ROWS_PER_BLOCK) * E_DIM + i];
    __syncthreads();

    float* wscratch = scratch[w];
    const int lbase = chunk * ROWS_PER_BLOCK + w * ROWS_PER_WAVE;

    // ---- Phase A: 6 dot-rows, no fences between ----
    #pragma unroll
    for (int j = 0; j < ROWS_PER_WAVE; ++j) {
        const int lrow = w * ROWS_PER_WAVE + j;
        const int l    = lbase + j;
        const int fi   = l >> 3;
        const int vi   = l & 7;
        int r;
        if (lane < 48) {
            r = (lane <= fi) ? (fi - lane) : (F_DIM + lane - fi);
        } else {
            r = 96 + vi * 8 + ((lane - 48) & 7);
        }
        const f32x4* qv = (const f32x4*)&qs[lrow * E_DIM];   // wave-broadcast reads
        const f32x4* tv = (const f32x4*)&tabs[r * TSTRIDE];
        f32x4 acc = qv[0] * tv[0] + qv[1] * tv[1] + qv[2] * tv[2] + qv[3] * tv[3];
        const float s = acc.x + acc.y + acc.z + acc.w;
        if (lane < 56) wscratch[j * 64 + lane] = s;          // T[0..47], V[0..7]
    }
    // One fence: all 6 rows' ds_writes drained; wave-local so no block barrier.
    asm volatile("s_waitcnt lgkmcnt(0)" ::: "memory");
    __builtin_amdgcn_wave_barrier();

    // ---- Phase B: 6 rows x 2 float4-store instructions, back-to-back ----
    #pragma unroll
    for (int j = 0; j < ROWS_PER_WAVE; ++j) {
        const int l = lbase + j;
        float* orow = out + ((size_t)bh * L_IN + l) * L_OUT;
        const float* ws_ = &wscratch[j * 64];
        #pragma unroll
        for (int rr = 0; rr < 2; ++rr) {
            const int jj = rr * 64 + lane;    // vec4 index [0, 96)
            if (jj < 96) {
                const float tval = ws_[jj >> 1];                    // T[m>>3]
                const f32x4 vv = *(const f32x4*)&ws_[48 + 4 * (jj & 1)]; // V[m&7..]
                f32x4 o;
                o.x = tval + vv.x; o.y = tval + vv.y;
                o.z = tval + vv.z; o.w = tval + vv.w;
                *(f32x4*)(orow + 4 * jj) = o;   // plain store: let L2 absorb
            }
        }
    }
}

extern "C" void kernel_launch(void* const* d_in, const int* in_sizes, int n_in,
                              void* d_out, int out_size, void* d_ws, size_t ws_size,
                              hipStream_t stream) {
    const float* q        = (const float*)d_in[0];
    // d_in[1] = flipped_masks (unused)
    const float* r_voice  = (const float*)d_in[2];
    const float* e_past   = (const float*)d_in[3];
    const float* e_future = (const float*)d_in[4];
    float* out = (float*)d_out;

    dim3 grid(NCHUNK, SZ_B * H_DIM);  // (16, 32) = 512 blocks, 2/CU
    bsa_fused_kernel<<<grid, dim3(256), 0, stream>>>(q, r_voice, e_past, e_future, out);
}

// Round 8
// 11.520 us; speedup vs baseline: 1.1525x; 1.1525x over previous
//
#include <hip/hip_runtime.h>
#include <hip/hip_bf16.h>

// Constants from the reference
#define E_DIM 16
#define H_DIM 8
#define F_DIM 48
#define L_IN 384
#define L_OUT 384
#define SZ_B 4

#define NCHUNK 8            // l-chunks per bh (48 rows each)
#define ROWS_PER_BLOCK 48
#define ROWS_PER_WAVE 6
#define TSTRIDE 20          // padded table row stride (floats): 80 B, 16B-aligned b128 rows

typedef float f32x4 __attribute__((ext_vector_type(4)));

// out[bh, l, m] = sum_d q[bh,l,d] * ( r_voice[l%8, m%8, d, h] + rt(l/8, m/8, d, h) )
//   rt(fp,fq,d,h) = fp>=fq ? e_past[fp-fq,d,h] : e_future[fq-fp,d,h]
// Block = (chunk, bh), 512 threads, 1 block/CU. Tables staged once per block
// (fi-independent; indexed by |fi-fq| at dot time). Wave w owns 6 rows.
// q-rows are wave-uniform -> scalar (SGPR) loads, no LDS round-trip.
// Phase A: 6 dot-rows back-to-back (4 ds_read_b128 + 16 sgpr-FMA each).
// ONE lgkmcnt fence. Phase B: 12 nontemporal float4-store instructions.
__global__ __launch_bounds__(512)
void bsa_fused_kernel(const float* __restrict__ q,
                      const float* __restrict__ r_voice,
                      const float* __restrict__ e_past,
                      const float* __restrict__ e_future,
                      float* __restrict__ out) {
    const int chunk = blockIdx.x;   // [0, 8)
    const int bh    = blockIdx.y;   // [0, 32)
    const int h     = bh & (H_DIM - 1);
    const int t     = threadIdx.x;  // [0, 512)
    const int lane  = t & 63;

    // Table rows (stride 20): 0..47 past[diff], 48..95 future[diff], 96..159 voice
    __shared__ __attribute__((aligned(16))) float tabs[160 * TSTRIDE];        // 12.8 KB
    __shared__ __attribute__((aligned(16))) float scratch[8][ROWS_PER_WAVE * 64]; // 12 KB

    // Stage transposed tables (this block's h-plane). i = f*16+d; src = i*8+h.
    for (int i = t; i < F_DIM * E_DIM; i += 512) {
        const int f = i >> 4, d = i & 15;
        tabs[f * TSTRIDE + d]           = e_past [(size_t)i * H_DIM + h];
        tabs[(F_DIM + f) * TSTRIDE + d] = e_future[(size_t)i * H_DIM + h];
    }
    for (int i = t; i < 64 * E_DIM; i += 512) {
        const int r = i >> 4, d = i & 15;
        tabs[(96 + r) * TSTRIDE + d] = r_voice[(size_t)i * H_DIM + h];
    }
    __syncthreads();

    // Wave-uniform row base (readfirstlane-hoisted so q loads scalarize).
    const int wu    = __builtin_amdgcn_readfirstlane(t >> 6);   // wave id [0,8)
    const int lbase = chunk * ROWS_PER_BLOCK + wu * ROWS_PER_WAVE;
    float* wscratch = scratch[wu];

    // ---- Phase A: 6 dot-rows, no fences between ----
    #pragma unroll
    for (int j = 0; j < ROWS_PER_WAVE; ++j) {
        const int l  = lbase + j;
        const int fi = l >> 3;
        const int vi = l & 7;
        int r;
        if (lane < 48) {
            r = (lane <= fi) ? (fi - lane) : (F_DIM + lane - fi);
        } else {
            r = 96 + vi * 8 + ((lane - 48) & 7);
        }
        const f32x4* tv = (const f32x4*)&tabs[r * TSTRIDE];
        const f32x4 t0 = tv[0], t1 = tv[1], t2 = tv[2], t3 = tv[3];
        // Wave-uniform q-row: scalar loads -> SGPRs.
        const float* qrow = q + ((size_t)bh * L_IN + l) * E_DIM;
        float s = 0.f;
        s += qrow[0]  * t0.x + qrow[1]  * t0.y + qrow[2]  * t0.z + qrow[3]  * t0.w;
        s += qrow[4]  * t1.x + qrow[5]  * t1.y + qrow[6]  * t1.z + qrow[7]  * t1.w;
        s += qrow[8]  * t2.x + qrow[9]  * t2.y + qrow[10] * t2.z + qrow[11] * t2.w;
        s += qrow[12] * t3.x + qrow[13] * t3.y + qrow[14] * t3.z + qrow[15] * t3.w;
        if (lane < 56) wscratch[j * 64 + lane] = s;   // T[0..47], V[0..7]
    }
    // One fence: all scratch ds_writes drained (wave-local; no block barrier).
    asm volatile("s_waitcnt lgkmcnt(0)" ::: "memory");
    __builtin_amdgcn_wave_barrier();

    // ---- Phase B: 6 rows x 2 nontemporal float4-store instrs, back-to-back ----
    #pragma unroll
    for (int j = 0; j < ROWS_PER_WAVE; ++j) {
        const int l = lbase + j;
        float* orow = out + ((size_t)bh * L_IN + l) * L_OUT;
        const float* ws_ = &wscratch[j * 64];
        #pragma unroll
        for (int rr = 0; rr < 2; ++rr) {
            const int jj = rr * 64 + lane;    // vec4 index [0, 96)
            if (jj < 96) {
                const float tval = ws_[jj >> 1];                        // T[m>>3]
                const f32x4 vv = *(const f32x4*)&ws_[48 + 4 * (jj & 1)]; // V[m&7..]
                f32x4 o;
                o.x = tval + vv.x; o.y = tval + vv.y;
                o.z = tval + vv.z; o.w = tval + vv.w;
                __builtin_nontemporal_store(o, (f32x4*)(orow + 4 * jj));
            }
        }
    }
}

extern "C" void kernel_launch(void* const* d_in, const int* in_sizes, int n_in,
                              void* d_out, int out_size, void* d_ws, size_t ws_size,
                              hipStream_t stream) {
    const float* q        = (const float*)d_in[0];
    // d_in[1] = flipped_masks (unused)
    const float* r_voice  = (const float*)d_in[2];
    const float* e_past   = (const float*)d_in[3];
    const float* e_future = (const float*)d_in[4];
    float* out = (float*)d_out;

    dim3 grid(NCHUNK, SZ_B * H_DIM);  // (8, 32) = 256 blocks, 1/CU
    bsa_fused_kernel<<<grid, dim3(512), 0, stream>>>(q, r_voice, e_past, e_future, out);
}